// Round 1
// baseline (334.003 us; speedup 1.0000x reference)
//
#include <hip/hip_runtime.h>

// GridSample1d, align_corners=True, border padding.
// Shapes fixed by setup_inputs(): inp [64,64,4096] f32, grid [64,8192] f32,
// out [64,64,8192] f32.

constexpr int N_    = 64;
constexpr int C_    = 64;
constexpr int L_IN  = 4096;
constexpr int L_OUT = 8192;

constexpr int VEC    = 4;              // l positions per thread (float4 store)
constexpr int BLOCK  = 256;
constexpr int L_TILE = BLOCK * VEC;    // 1024
constexpr int C_TILE = 16;             // channels per block
constexpr int LCH    = L_OUT / L_TILE; // 8
constexpr int CCH    = C_ / C_TILE;    // 4
constexpr int NBLOCKS = N_ * LCH * CCH; // 2048

__global__ __launch_bounds__(BLOCK) void gs1d_kernel(
    const float* __restrict__ inp, const float* __restrict__ grid,
    float* __restrict__ out)
{
    int bid = blockIdx.x;
    int n   = bid / (LCH * CCH);
    int r   = bid % (LCH * CCH);
    int cc  = r / LCH;
    int lc  = r % LCH;

    int l0 = lc * L_TILE + threadIdx.x * VEC;

    // One float4 grid load per thread, amortized over C_TILE channels.
    float4 g = *reinterpret_cast<const float4*>(grid + (size_t)n * L_OUT + l0);
    float gv[VEC] = {g.x, g.y, g.z, g.w};

    int   i0[VEC], i1[VEC];
    float w0[VEC], w1[VEC];
#pragma unroll
    for (int j = 0; j < VEC; ++j) {
        // exact reference op order: ((g+1)*0.5)*(L-1), clip, floor
        float x = (gv[j] + 1.0f) * 0.5f * (float)(L_IN - 1);
        x = fminf(fmaxf(x, 0.0f), (float)(L_IN - 1));
        float xf = floorf(x);
        w1[j] = x - xf;
        w0[j] = 1.0f - w1[j];
        i0[j] = (int)xf;
        i1[j] = min(i0[j] + 1, L_IN - 1);
    }

    const float* in_base  = inp + (size_t)n * C_ * L_IN  + (size_t)cc * C_TILE * L_IN;
    float*       out_base = out + (size_t)n * C_ * L_OUT + (size_t)cc * C_TILE * L_OUT + l0;

#pragma unroll 4
    for (int c = 0; c < C_TILE; ++c) {
        const float* row = in_base + (size_t)c * L_IN;
        float v00 = row[i0[0]], v01 = row[i1[0]];
        float v10 = row[i0[1]], v11 = row[i1[1]];
        float v20 = row[i0[2]], v21 = row[i1[2]];
        float v30 = row[i0[3]], v31 = row[i1[3]];
        float4 o;
        o.x = fmaf(w0[0], v00, w1[0] * v01);
        o.y = fmaf(w0[1], v10, w1[1] * v11);
        o.z = fmaf(w0[2], v20, w1[2] * v21);
        o.w = fmaf(w0[3], v30, w1[3] * v31);
        *reinterpret_cast<float4*>(out_base + (size_t)c * L_OUT) = o;
    }
}

extern "C" void kernel_launch(void* const* d_in, const int* in_sizes, int n_in,
                              void* d_out, int out_size, void* d_ws, size_t ws_size,
                              hipStream_t stream) {
    const float* inp  = (const float*)d_in[0];
    const float* grid = (const float*)d_in[1];
    float* out = (float*)d_out;
    gs1d_kernel<<<NBLOCKS, BLOCK, 0, stream>>>(inp, grid, out);
}

// Round 2
// 185.356 us; speedup vs baseline: 1.8020x; 1.8020x over previous
//
#include <hip/hip_runtime.h>

// GridSample1d, align_corners=True, border padding.
// inp [64,64,4096] f32, grid [64,8192] f32, out [64,64,8192] f32.
//
// Strategy: random gathers go to LDS (divergence-tolerant), not global.
// Block = (n, 4-channel chunk): stage 4 rows (64 KB) -> LDS once, compute
// grid indices once per thread, reuse over 4 channels. Input read from HBM
// exactly once; output written with coalesced float4 stores.

constexpr int N_    = 64;
constexpr int C_    = 64;
constexpr int L_IN  = 4096;
constexpr int L_OUT = 8192;

constexpr int BLOCK   = 1024;          // 16 waves
constexpr int C_LDS   = 4;             // rows staged per block (64 KB LDS)
constexpr int NCHUNK  = C_ / C_LDS;    // 16
constexpr int NBLOCKS = N_ * NCHUNK;   // 1024 blocks -> 2 resident/CU

__global__ __launch_bounds__(BLOCK, 8) void gs1d_kernel(
    const float* __restrict__ inp, const float* __restrict__ grid,
    float* __restrict__ out)
{
    __shared__ float lds[C_LDS * L_IN];  // 64 KB

    const int tid = threadIdx.x;
    const int bid = blockIdx.x;
    const int n   = bid >> 4;          // / NCHUNK
    const int cc  = bid & (NCHUNK - 1);

    const float* src = inp + ((size_t)n * C_ + (size_t)cc * C_LDS) * L_IN;

    // Async stage 64 KB global -> LDS: 4 calls x (1024 lanes x 16 B).
    // LDS dest is wave-uniform base + lane*16 (m97/m104 semantics).
#pragma unroll
    for (int k = 0; k < 4; ++k) {
        int e     = (k * BLOCK + tid) * 4;          // per-lane float index
        int lbase = (k * BLOCK + (tid & ~63)) * 4;  // wave-uniform float index
        __builtin_amdgcn_global_load_lds(
            (const __attribute__((address_space(1))) void*)(src + e),
            (__attribute__((address_space(3))) void*)(&lds[lbase]),
            16, 0, 0);
    }

    // Grid coords for this thread's 8 output positions (2 chunks of 4),
    // overlapped with the staging DMA.
    const float* grow = grid + (size_t)n * L_OUT;
    float4 g0 = *reinterpret_cast<const float4*>(grow + 4 * tid);
    float4 g1 = *reinterpret_cast<const float4*>(grow + L_OUT / 2 + 4 * tid);

    float gv[8] = {g0.x, g0.y, g0.z, g0.w, g1.x, g1.y, g1.z, g1.w};
    int   li[8];
    float w1[8];
#pragma unroll
    for (int j = 0; j < 8; ++j) {
        // exact reference op order: ((g+1)*0.5)*(L-1), clip, floor
        float x = (gv[j] + 1.0f) * 0.5f * (float)(L_IN - 1);
        x = fminf(fmaxf(x, 0.0f), (float)(L_IN - 1));
        float xf = floorf(x);
        int   i0 = (int)xf;
        float w  = x - xf;
        // boundary trick: at i0 == L-1 (w==0), shift to (li=L-2, w1=1) so the
        // unconditional lerp row[li] + w1*(row[li+1]-row[li]) stays exact.
        li[j] = min(i0, L_IN - 2);
        w1[j] = (i0 >= L_IN - 1) ? 1.0f : w;
    }

    __syncthreads();

    float* out_base = out + ((size_t)n * C_ + (size_t)cc * C_LDS) * L_OUT;

#pragma unroll
    for (int c = 0; c < C_LDS; ++c) {
        const float* row = &lds[c * L_IN];
#pragma unroll
        for (int h = 0; h < 2; ++h) {
            float4 o;
            float* op = &o.x;
#pragma unroll
            for (int j = 0; j < 4; ++j) {
                int   p = h * 4 + j;
                float a = row[li[p]];       // ds_read2_b32 pair
                float b = row[li[p] + 1];
                op[j] = fmaf(w1[p], b - a, a);
            }
            *reinterpret_cast<float4*>(
                out_base + (size_t)c * L_OUT + h * (L_OUT / 2) + 4 * tid) = o;
        }
    }
}

extern "C" void kernel_launch(void* const* d_in, const int* in_sizes, int n_in,
                              void* d_out, int out_size, void* d_ws, size_t ws_size,
                              hipStream_t stream) {
    const float* inp  = (const float*)d_in[0];
    const float* grid = (const float*)d_in[1];
    float* out = (float*)d_out;
    gs1d_kernel<<<NBLOCKS, BLOCK, 0, stream>>>(inp, grid, out);
}

// Round 3
// 183.707 us; speedup vs baseline: 1.8181x; 1.0090x over previous
//
#include <hip/hip_runtime.h>

// GridSample1d, align_corners=True, border padding.
// inp [64,64,4096] f32, grid [64,8192] f32, out [64,64,8192] f32.
//
// One block per (n,c): stage the 16 KB input row into LDS (global_load_lds
// width=16), gather with ds_read2 (LDS tolerates address divergence), write
// coalesced nontemporal float4. 256-thread blocks + 16 KB LDS -> 8 blocks/CU
// so stage-DMA of some blocks overlaps gather/store of others.

constexpr int N_    = 64;
constexpr int C_    = 64;
constexpr int L_IN  = 4096;
constexpr int L_OUT = 8192;

constexpr int BLOCK  = 256;
constexpr int CHUNKS = L_OUT / (BLOCK * 4);  // 8 float4-chunks per thread
constexpr int NBLOCKS = N_ * C_;             // 4096

typedef float f32x4 __attribute__((ext_vector_type(4)));

__global__ __launch_bounds__(BLOCK, 8) void gs1d_kernel(
    const float* __restrict__ inp, const float* __restrict__ grid,
    float* __restrict__ out)
{
    __shared__ float row[L_IN];  // 16 KB

    const int tid = threadIdx.x;
    const int bid = blockIdx.x;      // n*64 + c
    const int n   = bid >> 6;

    // Stage this (n,c) input row -> LDS: 4 calls x (256 lanes x 16 B).
    // LDS dest semantics: wave-uniform base + lane*16 (m97/m104).
    const float* src = inp + (size_t)bid * L_IN;
#pragma unroll
    for (int k = 0; k < 4; ++k) {
        int e     = (k * BLOCK + tid) * 4;          // per-lane float index
        int lbase = (k * BLOCK + (tid & ~63)) * 4;  // wave-uniform float index
        __builtin_amdgcn_global_load_lds(
            (const __attribute__((address_space(1))) void*)(src + e),
            (__attribute__((address_space(3))) void*)(&row[lbase]),
            16, 0, 0);
    }

    const float* grow = grid + (size_t)n * L_OUT;
    float*       orow = out  + (size_t)bid * L_OUT;

    // Two halves of 4 chunks: prefetch 4 grid float4s (16 VGPR), then
    // compute — keeps VGPR < 64 so (256,8) doesn't spill.
#pragma unroll
    for (int half = 0; half < 2; ++half) {
        float4 g[4];
#pragma unroll
        for (int h = 0; h < 4; ++h)
            g[h] = *reinterpret_cast<const float4*>(
                grow + (half * 4 + h) * (BLOCK * 4) + 4 * tid);

        if (half == 0) __syncthreads();  // drain stage DMA once

#pragma unroll
        for (int h = 0; h < 4; ++h) {
            const float* gp = &g[h].x;
            f32x4 o;
#pragma unroll
            for (int j = 0; j < 4; ++j) {
                // exact reference op order: ((g+1)*0.5)*(L-1), clip, floor
                float x = (gp[j] + 1.0f) * 0.5f * (float)(L_IN - 1);
                x = fminf(fmaxf(x, 0.0f), (float)(L_IN - 1));
                float xf = floorf(x);
                int   i0 = (int)xf;
                float w  = x - xf;
                // boundary: at i0==L-1 shift to (li=L-2, w1=1) so the
                // unconditional lerp a + w1*(b-a) stays exact.
                int   li = min(i0, L_IN - 2);
                float w1 = (i0 >= L_IN - 1) ? 1.0f : w;
                float a = row[li];       // ds_read2_b32 pair
                float b = row[li + 1];
                o[j] = fmaf(w1, b - a, a);
            }
            __builtin_nontemporal_store(o,
                reinterpret_cast<f32x4*>(
                    orow + (half * 4 + h) * (BLOCK * 4) + 4 * tid));
        }
    }
}

extern "C" void kernel_launch(void* const* d_in, const int* in_sizes, int n_in,
                              void* d_out, int out_size, void* d_ws, size_t ws_size,
                              hipStream_t stream) {
    const float* inp  = (const float*)d_in[0];
    const float* grid = (const float*)d_in[1];
    float* out = (float*)d_out;
    gs1d_kernel<<<NBLOCKS, BLOCK, 0, stream>>>(inp, grid, out);
}

// Round 4
// 182.833 us; speedup vs baseline: 1.8268x; 1.0048x over previous
//
#include <hip/hip_runtime.h>

// GridSample1d, align_corners=True, border padding.
// inp [64,64,4096] f32, grid [64,8192] f32, out [64,64,8192] f32.
//
// One block per (n,c) row. Key change vs R3: ALL grid loads + index math are
// hoisted BEFORE the barrier (results in registers), so each block's 16 KB
// global->LDS DMA is hidden behind its own VALU phase instead of stalling at
// the barrier. Post-barrier phase is pure LDS gather + NT float4 stores.
// launch_bounds(256,4): VGPR<=128 (need ~110 for li/w1 arrays) -> 4 blocks/CU.

constexpr int N_    = 64;
constexpr int C_    = 64;
constexpr int L_IN  = 4096;
constexpr int L_OUT = 8192;

constexpr int BLOCK = 256;
constexpr int EPT   = L_OUT / BLOCK;   // 32 elements per thread
constexpr int NCH   = EPT / 4;         // 8 float4 chunks
constexpr int NBLOCKS = N_ * C_;       // 4096

typedef float f32x4 __attribute__((ext_vector_type(4)));

__global__ __launch_bounds__(BLOCK, 4) void gs1d_kernel(
    const float* __restrict__ inp, const float* __restrict__ grid,
    float* __restrict__ out)
{
    __shared__ float row[L_IN];  // 16 KB

    const int tid = threadIdx.x;
    const int bid = blockIdx.x;      // n*64 + c
    const int n   = bid >> 6;

    // Stage this (n,c) input row -> LDS: 4 x (256 lanes x 16 B) async DMA.
    // LDS dest semantics: wave-uniform base + lane*16 (m97/m104).
    const float* src = inp + (size_t)bid * L_IN;
#pragma unroll
    for (int k = 0; k < 4; ++k) {
        int e     = (k * BLOCK + tid) * 4;          // per-lane float index
        int lbase = (k * BLOCK + (tid & ~63)) * 4;  // wave-uniform float index
        __builtin_amdgcn_global_load_lds(
            (const __attribute__((address_space(1))) void*)(src + e),
            (__attribute__((address_space(3))) void*)(&row[lbase]),
            16, 0, 0);
    }

    const float* grow = grid + (size_t)n * L_OUT;

    // Pre-barrier: all grid loads + index math, results in registers.
    // ~380 VALU instrs/thread covers the DMA's in-flight time.
    int   li[EPT];
    float w1[EPT];
#pragma unroll
    for (int h = 0; h < NCH; ++h) {
        float4 g = *reinterpret_cast<const float4*>(grow + h * (BLOCK * 4) + 4 * tid);
        const float* gp = &g.x;
#pragma unroll
        for (int j = 0; j < 4; ++j) {
            // exact reference op order: ((g+1)*0.5)*(L-1), clip, floor
            float x = (gp[j] + 1.0f) * 0.5f * (float)(L_IN - 1);
            x = fminf(fmaxf(x, 0.0f), (float)(L_IN - 1));
            float xf = floorf(x);
            int   i0 = (int)xf;
            float w  = x - xf;
            // boundary: at i0==L-1 shift to (li=L-2, w1=1) so the
            // unconditional lerp a + w1*(b-a) stays exact.
            li[h * 4 + j] = min(i0, L_IN - 2);
            w1[h * 4 + j] = (i0 >= L_IN - 1) ? 1.0f : w;
        }
    }

    __syncthreads();  // DMA latency already covered by the index phase

    float* orow = out + (size_t)bid * L_OUT;

    // Post-barrier: pure LDS gather + lerp + nontemporal coalesced stores.
#pragma unroll
    for (int h = 0; h < NCH; ++h) {
        f32x4 o;
#pragma unroll
        for (int j = 0; j < 4; ++j) {
            int   p = h * 4 + j;
            float a = row[li[p]];       // ds_read2_b32 pair
            float b = row[li[p] + 1];
            o[j] = fmaf(w1[p], b - a, a);
        }
        __builtin_nontemporal_store(o,
            reinterpret_cast<f32x4*>(orow + h * (BLOCK * 4) + 4 * tid));
    }
}

extern "C" void kernel_launch(void* const* d_in, const int* in_sizes, int n_in,
                              void* d_out, int out_size, void* d_ws, size_t ws_size,
                              hipStream_t stream) {
    const float* inp  = (const float*)d_in[0];
    const float* grid = (const float*)d_in[1];
    float* out = (float*)d_out;
    gs1d_kernel<<<NBLOCKS, BLOCK, 0, stream>>>(inp, grid, out);
}